// Round 8
// baseline (61.239 us; speedup 1.0000x reference)
//
#include <hip/hip_runtime.h>

#define FLOOR_EPS 1e-6f

// Problem shape (from reference): B=32, C=1, F=128, T=8000
constexpr int Bq = 32, Cq = 1, Fq = 128, Tq = 8000;
constexpr int ROWS  = Bq * Cq * Fq;             // 4096 independent rows
constexpr int LPR   = 16;                       // elems per lane per round (4 float4)
constexpr int RNDE  = 64 * LPR;                 // 1024 elems per round per wave
constexpr int SPLIT = 4;                        // segments per row (temporal split)
constexpr int MAIN  = Tq / SPLIT;               // 2000 elems per segment
constexpr int NRM   = (MAIN + RNDE - 1) / RNDE; // 2 main rounds (last partial: 976)
constexpr int LACT  = (MAIN - (NRM - 1) * RNDE) / LPR; // 61 active lanes, last round
constexpr int WPB   = 4;                        // waves per block -> block == one row
constexpr int NSEG  = ROWS * SPLIT;             // 16384 waves
constexpr unsigned TOTE = (unsigned)ROWS * Tq;  // total elements (fits 32-bit)

__global__ __launch_bounds__(256)
void _PCEN_75033078661345_kernel(const float* __restrict__ x,
                                 const float* __restrict__ alpha,
                                 const float* __restrict__ delta,
                                 const float* __restrict__ root,
                                 const float* __restrict__ smooth,
                                 float* __restrict__ out,   // ROWS*T
                                 float* __restrict__ hid)   // ROWS
{
    const int lane = threadIdx.x & 63;
    const int h    = threadIdx.x >> 6;         // quarter index (block == one row)
    const int r    = blockIdx.x;               // row

    // Cq==1 -> channel params uniform
    const float w   = fminf(fmaxf(smooth[0], 0.f), 1.f);
    const float om  = 1.f - w;
    const float aa  = fminf(alpha[0], 1.f);
    const float dd  = delta[0];
    const float oor = 1.f / fmaxf(root[0], 1.f);
    const bool  us  = (oor == 0.5f);
    const float droot = us ? __builtin_amdgcn_sqrtf(dd)
                           : __builtin_amdgcn_exp2f(oor * __builtin_amdgcn_logf(dd));

    // omp[k] = om^(16 * 2^k) by squaring; om16i = om^(16*lane); omR = om^1024
    float om2 = om * om, om4 = om2 * om2, om8 = om4 * om4;
    float omp[6];
    omp[0] = om8 * om8;                        // om^16
    #pragma unroll
    for (int k = 1; k < 6; ++k) omp[k] = omp[k - 1] * omp[k - 1];
    float om16i = 1.f;
    #pragma unroll
    for (int k = 0; k < 6; ++k) om16i = ((lane >> k) & 1) ? om16i * omp[k] : om16i;
    const float omR = omp[5] * omp[5];         // om^1024

    // Warmup rounds for h>0: window W=Rw*1024 with om^W <= ~2^-30 (runtime-adaptive)
    int Rw = 0;
    if (h) {
        const float nl2 = fmaxf(-__builtin_amdgcn_logf(om), 1e-9f); // -log2(om)
        int ri = (int)ceilf(30.f / (1024.f * nl2));
        const int cap = (h * MAIN) / RNDE;     // keep w0 >= 0
        Rw = ri < 1 ? 1 : ri;
        Rw = Rw > 2 ? 2 : Rw;
        Rw = Rw > cap ? cap : Rw;
    }
    const int w0 = h * MAIN - Rw * RNDE;       // first round's base element in row
    const int nr = NRM + Rw;                   // rounds this wave: 2 (h=0) or 3/4

    const unsigned rowbase = (unsigned)r * (unsigned)Tq;

    float carry = x[rowbase + (unsigned)w0];   // EMA state entering element w0
    float accv  = 0.f;

    auto LOADR = [&](int sidx, float4& d0, float4& d1, float4& d2, float4& d3) {
        unsigned u = rowbase + (unsigned)(w0 + sidx * RNDE + lane * LPR);
        u = u > (TOTE - LPR) ? (TOTE - LPR) : u;   // clamp only at buffer end
        const float4* p = (const float4*)(x + u);
        d0 = p[0]; d1 = p[1]; d2 = p[2]; d3 = p[3];
    };

    auto ROUND = [&](int sidx, float4 c0, float4 c1, float4 c2, float4 c3) {
        const float xv[LPR] = {c0.x, c0.y, c0.z, c0.w, c1.x, c1.y, c1.z, c1.w,
                               c2.x, c2.y, c2.z, c2.w, c3.x, c3.y, c3.z, c3.w};
        // local affine offset over 16 elems (coefficient om^16 uniform)
        float b = 0.f;
        #pragma unroll
        for (int j = 0; j < LPR; ++j) b = w * xv[j] + om * b;
        // Kogge-Stone scan with constant per-level coefficient: 6 shuffles
        #pragma unroll
        for (int k = 0; k < 6; ++k) {
            const float pb = __shfl_up(b, 1 << k);
            const float nb = fmaf(omp[k], pb, b);
            b = (lane >= (1 << k)) ? nb : b;
        }
        const float pb1  = __shfl_up(b, 1);
        const float bex  = (lane == 0) ? 0.f : pb1;
        float acc        = fmaf(om16i, carry, bex);  // state entering this lane
        const float btot = __shfl(b, 63);
        carry = fmaf(omR, carry, btot);              // state after this round
        if (sidx >= Rw) {                            // main region: pointwise + store
            float ov[LPR];
            #pragma unroll
            for (int j = 0; j < LPR; ++j) {
                acc = w * xv[j] + om * acc;          // exact sequential EMA
                const float dp = __builtin_amdgcn_exp2f(-aa * __builtin_amdgcn_logf(FLOOR_EPS + acc));
                const float tt = fmaf(xv[j], dp, dd);
                ov[j] = us ? (__builtin_amdgcn_sqrtf(tt) - droot)
                           : (__builtin_amdgcn_exp2f(oor * __builtin_amdgcn_logf(tt)) - droot);
            }
            const bool lastr = (sidx == nr - 1);
            if (!lastr || lane < LACT) {
                float4* q = (float4*)(out + rowbase + (unsigned)(w0 + sidx * RNDE + lane * LPR));
                q[0] = {ov[0],  ov[1],  ov[2],  ov[3]};
                q[1] = {ov[4],  ov[5],  ov[6],  ov[7]};
                q[2] = {ov[8],  ov[9],  ov[10], ov[11]};
                q[3] = {ov[12], ov[13], ov[14], ov[15]};
            }
            accv = acc;
        }
    };

    // ---- static pipeline over nr in {2,3,4}: loads issue one round ahead ----
    float4 A0, A1, A2, A3, B0, B1, B2, B3;
    LOADR(0, A0, A1, A2, A3);
    LOADR(1, B0, B1, B2, B3);
    ROUND(0, A0, A1, A2, A3);
    if (nr == 2) {
        ROUND(1, B0, B1, B2, B3);
    } else if (nr == 3) {
        LOADR(2, A0, A1, A2, A3);
        ROUND(1, B0, B1, B2, B3);
        ROUND(2, A0, A1, A2, A3);
    } else {                                   // nr == 4 (small-om fallback)
        LOADR(2, A0, A1, A2, A3);
        ROUND(1, B0, B1, B2, B3);
        LOADR(3, B0, B1, B2, B3);
        ROUND(2, A0, A1, A2, A3);
        ROUND(3, B0, B1, B2, B3);
    }

    // hidden state = final EMA of the row (last-quarter wave, lane LACT-1)
    const float hh = __shfl(accv, LACT - 1);
    if (h == SPLIT - 1 && lane == 0) hid[r] = hh;
}

extern "C" void kernel_launch(void* const* d_in, const int* in_sizes, int n_in,
                              void* d_out, int out_size, void* d_ws, size_t ws_size,
                              hipStream_t stream) {
    const float* x      = (const float*)d_in[0];
    const float* alpha  = (const float*)d_in[1];
    const float* delta  = (const float*)d_in[2];
    const float* root   = (const float*)d_in[3];
    const float* smooth = (const float*)d_in[4];
    float* out = (float*)d_out;
    float* hid = out + (size_t)ROWS * Tq;

    _PCEN_75033078661345_kernel<<<NSEG / WPB, 256, 0, stream>>>(
        x, alpha, delta, root, smooth, out, hid);
}

// Round 9
// 55.120 us; speedup vs baseline: 1.1110x; 1.1110x over previous
//
#include <hip/hip_runtime.h>

#define FLOOR_EPS 1e-6f

// Problem shape (from reference): B=32, C=1, F=128, T=8000
constexpr int Bq = 32, Cq = 1, Fq = 128, Tq = 8000;
constexpr int ROWS  = Bq * Cq * Fq;             // 4096 independent rows
constexpr int LPR   = 8;                        // elems per lane per round (2 float4)
constexpr int RNDE  = 64 * LPR;                 // 512 elems per round per wave
constexpr int SPLIT = 2;                        // segments per row (temporal split)
constexpr int MAIN  = Tq / SPLIT;               // 4000 elems per segment
constexpr int NRM   = (MAIN + RNDE - 1) / RNDE; // 8 main rounds (last partial)
constexpr int LACT  = (MAIN - (NRM - 1) * RNDE) / LPR; // 52 active lanes, last round
constexpr int WPB   = 4;                        // waves per block
constexpr int NSEG  = ROWS * SPLIT;             // 8192 waves
constexpr unsigned TOTE = (unsigned)ROWS * Tq;  // total elements (fits 32-bit)

__global__ __launch_bounds__(256)
void _PCEN_75033078661345_kernel(const float* __restrict__ x,
                                 const float* __restrict__ alpha,
                                 const float* __restrict__ delta,
                                 const float* __restrict__ root,
                                 const float* __restrict__ smooth,
                                 float* __restrict__ out,   // ROWS*T
                                 float* __restrict__ hid)   // ROWS
{
    const int lane = threadIdx.x & 63;
    const int wid  = threadIdx.x >> 6;
    const int gw   = blockIdx.x * WPB + wid;   // global wave id
    const int r    = gw >> 1;                  // row
    const int h    = gw & 1;                   // which half of the row

    // Cq==1 -> channel params uniform
    const float w   = fminf(fmaxf(smooth[0], 0.f), 1.f);
    const float om  = 1.f - w;
    const float aa  = fminf(alpha[0], 1.f);
    const float dd  = delta[0];
    const float oor = 1.f / fmaxf(root[0], 1.f);
    const bool  us  = (oor == 0.5f);
    const float droot = us ? __builtin_amdgcn_sqrtf(dd)
                           : __builtin_amdgcn_exp2f(oor * __builtin_amdgcn_logf(dd));

    // omp[k] = om^(8 * 2^k) by squaring; om8i = om^(8*lane); omR = om^512
    float om2 = om * om, om4 = om2 * om2;
    float omp[6];
    omp[0] = om4 * om4;
    #pragma unroll
    for (int k = 1; k < 6; ++k) omp[k] = omp[k - 1] * omp[k - 1];
    float om8i = 1.f;
    #pragma unroll
    for (int k = 0; k < 6; ++k) om8i = ((lane >> k) & 1) ? om8i * omp[k] : om8i;
    const float omR = omp[5] * omp[5];

    // Warmup rounds for h=1: window W=Rw*512 with om^W <= ~2^-30 (runtime-adaptive)
    int Rw = 0;
    if (h) {
        const float nl2 = fmaxf(-__builtin_amdgcn_logf(om), 1e-9f); // -log2(om)
        int ri = (int)ceilf(30.f / (512.f * nl2));
        Rw = ri < 1 ? 1 : (ri > 7 ? 7 : ri);   // cap keeps w0 >= 0
    }
    const int w0 = h * MAIN - Rw * RNDE;       // first round's base element in row
    const int nr = NRM + Rw;                   // total rounds this wave (8..15)

    const unsigned rowbase = (unsigned)r * (unsigned)Tq;

    float carry = x[rowbase + (unsigned)w0];   // EMA state entering element w0
    float accv  = 0.f;

    auto LOADR = [&](int sidx, float4& d0, float4& d1) {
        unsigned u = rowbase + (unsigned)(w0 + sidx * RNDE + lane * LPR);
        u = u > (TOTE - LPR) ? (TOTE - LPR) : u;   // clamp only at buffer end
        const float4* p = (const float4*)(x + u);
        d0 = p[0]; d1 = p[1];
    };

    auto ROUND = [&](int sidx, float4 c0, float4 c1) {
        const float xv[LPR] = {c0.x, c0.y, c0.z, c0.w, c1.x, c1.y, c1.z, c1.w};
        // local affine offset over 8 elems (coefficient om^8 uniform)
        float b = 0.f;
        #pragma unroll
        for (int j = 0; j < LPR; ++j) b = w * xv[j] + om * b;
        // Kogge-Stone scan with constant per-level coefficient: 6 shuffles
        #pragma unroll
        for (int k = 0; k < 6; ++k) {
            const float pb = __shfl_up(b, 1 << k);
            const float nb = fmaf(omp[k], pb, b);
            b = (lane >= (1 << k)) ? nb : b;
        }
        const float pb1  = __shfl_up(b, 1);
        const float bex  = (lane == 0) ? 0.f : pb1;
        float acc        = fmaf(om8i, carry, bex);   // state entering this lane
        const float btot = __shfl(b, 63);
        carry = fmaf(omR, carry, btot);              // state after this round
        if (sidx >= Rw) {                            // main region: pointwise + store
            float ov[LPR];
            #pragma unroll
            for (int j = 0; j < LPR; ++j) {
                acc = w * xv[j] + om * acc;          // exact sequential EMA
                const float dp = __builtin_amdgcn_exp2f(-aa * __builtin_amdgcn_logf(FLOOR_EPS + acc));
                const float tt = fmaf(xv[j], dp, dd);
                ov[j] = us ? (__builtin_amdgcn_sqrtf(tt) - droot)
                           : (__builtin_amdgcn_exp2f(oor * __builtin_amdgcn_logf(tt)) - droot);
            }
            const bool lastr = (sidx == nr - 1);
            if (!lastr || lane < LACT) {
                float4* q = (float4*)(out + rowbase + (unsigned)(w0 + sidx * RNDE + lane * LPR));
                float4 o0 = {ov[0], ov[1], ov[2], ov[3]};
                float4 o1 = {ov[4], ov[5], ov[6], ov[7]};
                q[0] = o0; q[1] = o1;
            }
            accv = acc;
        }
    };

    // ---- 4-deep software pipeline, named buffers (all indices static) ----
    float4 P00, P01, P10, P11, P20, P21, P30, P31;
    LOADR(0, P00, P01); LOADR(1, P10, P11);
    LOADR(2, P20, P21); LOADR(3, P30, P31);
    int s = 0;
    for (; s + 3 < nr; s += 4) {
        ROUND(s,     P00, P01); if (s + 4 < nr) LOADR(s + 4, P00, P01);
        ROUND(s + 1, P10, P11); if (s + 5 < nr) LOADR(s + 5, P10, P11);
        ROUND(s + 2, P20, P21); if (s + 6 < nr) LOADR(s + 6, P20, P21);
        ROUND(s + 3, P30, P31); if (s + 7 < nr) LOADR(s + 7, P30, P31);
    }
    if (s     < nr) ROUND(s,     P00, P01);
    if (s + 1 < nr) ROUND(s + 1, P10, P11);
    if (s + 2 < nr) ROUND(s + 2, P20, P21);
    if (s + 3 < nr) ROUND(s + 3, P30, P31);

    // hidden state = final EMA of the row (second-half wave, lane LACT-1)
    const float hh = __shfl(accv, LACT - 1);
    if (h == SPLIT - 1 && lane == 0) hid[r] = hh;
}

extern "C" void kernel_launch(void* const* d_in, const int* in_sizes, int n_in,
                              void* d_out, int out_size, void* d_ws, size_t ws_size,
                              hipStream_t stream) {
    const float* x      = (const float*)d_in[0];
    const float* alpha  = (const float*)d_in[1];
    const float* delta  = (const float*)d_in[2];
    const float* root   = (const float*)d_in[3];
    const float* smooth = (const float*)d_in[4];
    float* out = (float*)d_out;
    float* hid = out + (size_t)ROWS * Tq;

    _PCEN_75033078661345_kernel<<<NSEG / WPB, 256, 0, stream>>>(
        x, alpha, delta, root, smooth, out, hid);
}